// Round 5
// baseline (100.899 us; speedup 1.0000x reference)
//
#include <hip/hip_runtime.h>
#include <cstdint>
#include <cstddef>

// MemristorDense: y[b,o] = C * sum_i [ exp2(Ep*L + Wp) - exp2(En*L + Wn) ]
// L[b,i]=log2(2x), E=log2(n), W=log2(kG*|w|+G_MIN), C=0.5*maxw/(G_MAX-G_MIN).
// x>=0 so sign handled by exp2(-inf)=0 at x==0.
// R5: no scalar loads in k_main's loop (SMEM is out-of-order -> lgkmcnt(0)
// full drains defeated prefetch); log2s hoisted to k_ew table.

#define B128 128
#define NIN  1024
#define NI   1025
#define NO   512
#define NJ   1024
#define SPLITS 32
#define CHUNK  33   // ceil(1025/32)
#define GMIN 1.0e-5f
#define GSPAN (1.0e-3f - 1.0e-5f)

__device__ __forceinline__ float flog2(float x) { return __builtin_amdgcn_logf(x); }
__device__ __forceinline__ float fexp2(float x) { return __builtin_amdgcn_exp2f(x); }

// Kernel 1 (grid 256 x 1024): zero out, LT[i][b]=1+log2(x[b][i]), block max -> bmax[256].
__global__ __launch_bounds__(1024) void k_prep(
    const float* __restrict__ x,
    const float* __restrict__ wp, const float* __restrict__ wn,
    const float* __restrict__ bp, const float* __restrict__ bn,
    float* __restrict__ LT, float* __restrict__ bmax, float* __restrict__ out)
{
    const int tid = blockIdx.x * 1024 + threadIdx.x;   // [0, 262144)

    if (tid < B128 * NO) out[tid] = 0.0f;

    if (tid < NI * B128) {
        int i = tid >> 7, b = tid & 127;
        float xv = (i < NIN) ? x[b * NIN + i] : 1.0f;
        LT[tid] = 1.0f + flog2(xv);                 // log2(2x); x=0 -> -inf (correct)
    }

    // NIN*NO = 524288 = 2 * 262144 exactly
    float m = fmaxf(fmaxf(__builtin_fabsf(wp[tid]), __builtin_fabsf(wn[tid])),
                    fmaxf(__builtin_fabsf(wp[tid + 262144]), __builtin_fabsf(wn[tid + 262144])));
    if (tid < NO) m = fmaxf(m, fmaxf(__builtin_fabsf(bp[tid]), __builtin_fabsf(bn[tid])));

    __shared__ float red[16];
    #pragma unroll
    for (int off = 32; off > 0; off >>= 1) m = fmaxf(m, __shfl_down(m, off, 64));
    if ((threadIdx.x & 63) == 0) red[threadIdx.x >> 6] = m;
    __syncthreads();
    if (threadIdx.x < 16) {
        m = red[threadIdx.x];
        #pragma unroll
        for (int off = 8; off > 0; off >>= 1) m = fmaxf(m, __shfl_down(m, off, 16));
        if (threadIdx.x == 0) bmax[blockIdx.x] = m;
    }
}

// Kernel 1b (grid 2050 x 256): EWT[i*NO+o] = (Ep, Wp, En, Wn) float4.
__global__ __launch_bounds__(256) void k_ew(
    const float* __restrict__ nd,
    const float* __restrict__ wp, const float* __restrict__ wn,
    const float* __restrict__ bp, const float* __restrict__ bn,
    const float* __restrict__ bmax, float4* __restrict__ EWT)
{
    __shared__ float smax;
    float m = bmax[threadIdx.x];
    #pragma unroll
    for (int off = 32; off > 0; off >>= 1) m = fmaxf(m, __shfl_down(m, off, 64));
    __shared__ float red[4];
    if ((threadIdx.x & 63) == 0) red[threadIdx.x >> 6] = m;
    __syncthreads();
    if (threadIdx.x == 0)
        smax = fmaxf(fmaxf(red[0], red[1]), fmaxf(red[2], red[3]));
    __syncthreads();
    const float kG = GSPAN / smax;

    const int tid = blockIdx.x * 256 + threadIdx.x;
    if (tid >= NI * NO) return;
    const int i = tid / NO, o = tid - i * NO;

    const float2 nv = *(const float2*)(nd + (size_t)i * NJ + 2 * o);
    const float wvp = (i < NIN) ? wp[i * NO + o] : bp[o];
    const float wvn = (i < NIN) ? wn[i * NO + o] : bn[o];

    float4 r;
    r.x = flog2(nv.x);
    r.y = flog2(__builtin_fmaf(kG, __builtin_fabsf(wvp), GMIN));
    r.z = flog2(nv.y);
    r.w = flog2(__builtin_fmaf(kG, __builtin_fabsf(wvn), GMIN));
    EWT[tid] = r;
}

// Kernel 2: grid (8 jtiles, 32 splits) x 1024 (16 waves, 8 batches/wave).
// Pure vector loads (no SMEM in loop); inner body: 1 dwordx4 EW + 2 dwordx4 L
// + 16 x {fma, exp2, add}.
__global__ __launch_bounds__(1024, 4) void k_main(
    const float4* __restrict__ EWT, const float* __restrict__ LT,
    const float* __restrict__ bmax, float* __restrict__ out)
{
    const int lane = threadIdx.x & 63;

    float m = fmaxf(fmaxf(bmax[lane], bmax[lane + 64]),
                    fmaxf(bmax[lane + 128], bmax[lane + 192]));
    #pragma unroll
    for (int off = 32; off > 0; off >>= 1) m = fmaxf(m, __shfl_down(m, off, 64));
    const float maxw = __shfl(m, 0, 64);
    const float C  = 0.5f * maxw / GSPAN;

    const int wvid = threadIdx.x >> 6;     // [0,16)
    const int b0 = wvid << 3;              // 8 batches/wave; plain VGPR -> vector loads
    const int o = (blockIdx.x << 6) + lane;
    const int i0 = blockIdx.y * CHUNK;
    int i1 = i0 + CHUNK; if (i1 > NI) i1 = NI;

    float accp[8], accn[8];
    #pragma unroll
    for (int k = 0; k < 8; ++k) { accp[k] = 0.0f; accn[k] = 0.0f; }

    float4 ew  = EWT[(size_t)i0 * NO + o];
    float4 L03 = *(const float4*)(LT + i0 * B128 + b0);
    float4 L47 = *(const float4*)(LT + i0 * B128 + b0 + 4);

    for (int i = i0; i < i1; ++i) {
        const int ip = (i + 1 < i1) ? i + 1 : i;
        float4 ew_n  = EWT[(size_t)ip * NO + o];
        float4 L03n = *(const float4*)(LT + ip * B128 + b0);
        float4 L47n = *(const float4*)(LT + ip * B128 + b0 + 4);

        const float Lv[8] = {L03.x, L03.y, L03.z, L03.w, L47.x, L47.y, L47.z, L47.w};
        #pragma unroll
        for (int bb = 0; bb < 8; ++bb) {
            accp[bb] += fexp2(__builtin_fmaf(ew.x, Lv[bb], ew.y));
            accn[bb] += fexp2(__builtin_fmaf(ew.z, Lv[bb], ew.w));
        }

        ew = ew_n; L03 = L03n; L47 = L47n;
    }

    #pragma unroll
    for (int bb = 0; bb < 8; ++bb) {
        unsafeAtomicAdd(out + (size_t)(b0 + bb) * NO + o, C * (accp[bb] - accn[bb]));
    }
}

extern "C" void kernel_launch(void* const* d_in, const int* in_sizes, int n_in,
                              void* d_out, int out_size, void* d_ws, size_t ws_size,
                              hipStream_t stream)
{
    const float* x  = (const float*)d_in[0];
    const float* wp = (const float*)d_in[1];
    const float* wn = (const float*)d_in[2];
    const float* bp = (const float*)d_in[3];
    const float* bn = (const float*)d_in[4];
    const float* nd = (const float*)d_in[5];
    float* out = (float*)d_out;

    unsigned char* ws = (unsigned char*)d_ws;
    float* bmax = (float*)ws;                     // 256 floats
    float* LT   = (float*)(ws + 4096);            // 1025*128*4 = 524800 B
    float4* EWT = (float4*)(ws + 4096 + 525056);  // 1025*512*16 = 8.4 MB

    k_prep<<<256, 1024, 0, stream>>>(x, wp, wn, bp, bn, LT, bmax, out);
    k_ew<<<2050, 256, 0, stream>>>(nd, wp, wn, bp, bn, bmax, EWT);
    k_main<<<dim3(8, SPLITS), 1024, 0, stream>>>(EWT, LT, bmax, out);
}